// Round 1
// baseline (2869.189 us; speedup 1.0000x reference)
//
#include <hip/hip_runtime.h>
#include <stdint.h>

typedef unsigned int uint32;

// Problem constants
#define NPOS_TOTAL 65536   // B*N = 4*16384
#define WPB 4              // waves per block
#define POS_PER_WAVE 32
#define NBLOCKS 512        // 512*4*32 = 65536 positions

__device__ __forceinline__ uint32 pack_bf16(float lo, float hi) {
  uint32 a = __builtin_bit_cast(uint32, lo);
  uint32 b = __builtin_bit_cast(uint32, hi);
  return ((b + 0x8000u) & 0xffff0000u) | ((a + 0x8000u) >> 16);
}
__device__ __forceinline__ float bf_lo(uint32 u) { return __builtin_bit_cast(float, u << 16); }
__device__ __forceinline__ float bf_hi(uint32 u) { return __builtin_bit_cast(float, u & 0xffff0000u); }
__device__ __forceinline__ float bcast(float v, int l) {
  return __builtin_bit_cast(float, __builtin_amdgcn_readlane(__builtin_bit_cast(int, v), l));
}

// ws layout (uint32 units):
// [0,4096)      gw1p   [o2][c]    pack(w1[c][o2],  w1[c][o2+64])     (w1: (64,128))
// [4096,8192)   gwoutp [c][o2]    pack(wout[o2][c], wout[o2+64][c])  (wout: (128,64))
// [8192,8704)   gcw2p  [j][l2]    pack(cw2[l2][j], cw2[l2+64][j])    (cw2: (128,8))
// [8704,9216)   gpw1   [q][m]     = pw1[m][q]  (float)               (pw1: (64,8))
// [9216,13312)  gpw2   [m2][m]    = pw2[m][m2] (float)               (pw2: (64,64))
// [13312,17408) gcw1p  [k][j2][c] pack(cw1[j2][c*16+k], cw1[j2+4][c*16+k]) (cw1: (8,1024))
__global__ void pack_weights_kernel(const float* __restrict__ w1, const float* __restrict__ pw1,
                                    const float* __restrict__ pw2, const float* __restrict__ cw2,
                                    const float* __restrict__ wout, const float* __restrict__ cw1,
                                    uint32* __restrict__ ws) {
  int t = threadIdx.x + blockIdx.x * blockDim.x;
  int stride = blockDim.x * gridDim.x;
  for (int i = t; i < 4096; i += stride) {
    int o2 = i >> 6, c = i & 63;
    ws[i] = pack_bf16(w1[c * 128 + o2], w1[c * 128 + o2 + 64]);
  }
  for (int i = t; i < 4096; i += stride) {
    int c = i >> 6, o2 = i & 63;
    ws[4096 + i] = pack_bf16(wout[o2 * 64 + c], wout[(o2 + 64) * 64 + c]);
  }
  for (int i = t; i < 512; i += stride) {
    int j = i >> 6, l2 = i & 63;
    ws[8192 + i] = pack_bf16(cw2[l2 * 8 + j], cw2[(l2 + 64) * 8 + j]);
  }
  float* wsf = (float*)ws;
  for (int i = t; i < 512; i += stride) {
    int q = i >> 6, m = i & 63;
    wsf[8704 + i] = pw1[m * 8 + q];
  }
  for (int i = t; i < 4096; i += stride) {
    int m2 = i >> 6, m = i & 63;
    wsf[9216 + i] = pw2[m * 64 + m2];
  }
  for (int i = t; i < 4096; i += stride) {
    int k = i >> 8, j2 = (i >> 6) & 3, c = i & 63;
    ws[13312 + i] = pack_bf16(cw1[j2 * 1024 + c * 16 + k], cw1[(j2 + 4) * 1024 + c * 16 + k]);
  }
}

__launch_bounds__(256, 2)
__global__ void pt_fused(const float* __restrict__ feats, const float* __restrict__ ppfs,
                         const float* __restrict__ w0, const float* __restrict__ b0,
                         const float* __restrict__ b1, const float* __restrict__ w2,
                         const float* __restrict__ b2, const float* __restrict__ w3,
                         const float* __restrict__ b3, const float* __restrict__ cb2,
                         const float* __restrict__ bout, const uint32* __restrict__ ws,
                         float* __restrict__ out) {
  // 64KB static LDS exactly
  __shared__ float  s_w0t[64 * 128];   // [c][o] = w0[o][c], fp32 (first matmul: keep precision)
  __shared__ uint32 s_w23p[128 * 64];  // [o][c] = pack(w2[c][o], w3[c][o])

  const int tid = threadIdx.x;
  const int lane = tid & 63;
  const int wv = tid >> 6;

  // Stage hot weights in LDS
  for (int i = tid; i < 8192; i += 256) {
    int c = i >> 7, o = i & 127;
    s_w0t[i] = w0[o * 64 + c];
  }
  for (int i = tid; i < 8192; i += 256) {
    int o = i >> 6, c = i & 63;
    s_w23p[i] = pack_bf16(w2[c * 128 + o], w3[c * 128 + o]);
  }
  __syncthreads();

  // Per-lane constant biases
  const float b0A = b0[lane], b0B = b0[lane + 64];
  const float b1r = b1[lane], b2r = b2[lane], b3r = b3[lane];
  const float cb2A = cb2[lane], cb2B = cb2[lane + 64];
  const float boutA = bout[lane], boutB = bout[lane + 64];

  const uint32* gw1p = ws;
  const uint32* gwoutp = ws + 4096;
  const uint32* gcw2p = ws + 8192;
  const float* gpw1 = (const float*)ws + 8704;
  const float* gpw2 = (const float*)ws + 9216;
  const uint32* gcw1p = ws + 13312;

  const int wgid = blockIdx.x * WPB + wv;
  const int p0 = wgid * POS_PER_WAVE;

  for (int pi = 0; pi < POS_PER_WAVE; ++pi) {
    const int p = p0 + pi;
    const int b = p >> 14, n = p & 16383;

    // ---- load feats: lane = input channel c, 16 contiguous floats (one cache line)
    const float* fp = feats + (((size_t)(b * 64 + lane)) * 16384 + n) * 16;
    float4 f0 = *(const float4*)(fp);
    float4 f1 = *(const float4*)(fp + 4);
    float4 f2 = *(const float4*)(fp + 8);
    float4 f3 = *(const float4*)(fp + 12);
    float f[16] = {f0.x, f0.y, f0.z, f0.w, f1.x, f1.y, f1.z, f1.w,
                   f2.x, f2.y, f2.z, f2.w, f3.x, f3.y, f3.z, f3.w};

    // ---- Phase A: xn[o][k] = relu(b0[o] + sum_c w0[o,c] f[c,k]); lane holds o=lane (A) and o=lane+64 (B)
    float xnA[16], xnB[16];
#pragma unroll
    for (int k = 0; k < 16; k++) { xnA[k] = b0A; xnB[k] = b0B; }
    for (int c = 0; c < 64; c++) {
      float wlo = s_w0t[c * 128 + lane];
      float whi = s_w0t[c * 128 + lane + 64];
#pragma unroll
      for (int k = 0; k < 16; k++) {
        float s = bcast(f[k], c);
        xnA[k] = fmaf(wlo, s, xnA[k]);
        xnB[k] = fmaf(whi, s, xnB[k]);
      }
    }
#pragma unroll
    for (int k = 0; k < 16; k++) { xnA[k] = fmaxf(xnA[k], 0.f); xnB[k] = fmaxf(xnB[k], 0.f); }

    // ---- Phase B: ptf = pw2 @ relu(pw1 @ ppfs)
    float ppA, ppB;
    {
      int q0 = lane >> 4, k0 = lane & 15;
      ppA = ppfs[(((size_t)(b * 8 + q0)) * 16384 + n) * 16 + k0];
      ppB = ppfs[(((size_t)(b * 8 + 4 + q0)) * 16384 + n) * 16 + k0];
    }
    float t[16];
#pragma unroll
    for (int k = 0; k < 16; k++) t[k] = 0.f;
    for (int q = 0; q < 8; q++) {
      float wq = gpw1[q * 64 + lane];
#pragma unroll
      for (int k = 0; k < 16; k++) {
        int idx = q * 16 + k;
        float s = (q < 4) ? bcast(ppA, idx) : bcast(ppB, idx - 64);
        t[k] = fmaf(wq, s, t[k]);
      }
    }
#pragma unroll
    for (int k = 0; k < 16; k++) t[k] = fmaxf(t[k], 0.f);
    float ptf[16];
#pragma unroll
    for (int k = 0; k < 16; k++) ptf[k] = 0.f;
    for (int m2 = 0; m2 < 64; m2++) {
      float wq = gpw2[m2 * 64 + lane];
#pragma unroll
      for (int k = 0; k < 16; k++) {
        float s = bcast(t[k], m2);
        ptf[k] = fmaf(wq, s, ptf[k]);
      }
    }

    // ---- Phase C: x2[c][k], x3[c][k] (lane = c), reduce over o = 0..127
    float x2a[16], x3a[16];
#pragma unroll
    for (int k = 0; k < 16; k++) { x2a[k] = b2r; x3a[k] = b3r; }
    for (int o = 0; o < 64; o++) {
      uint32 wp = s_w23p[o * 64 + lane];
      float w2v = bf_lo(wp), w3v = bf_hi(wp);
#pragma unroll
      for (int k = 0; k < 16; k++) {
        float s = bcast(xnA[k], o);
        x2a[k] = fmaf(w2v, s, x2a[k]);
        x3a[k] = fmaf(w3v, s, x3a[k]);
      }
    }
    for (int o = 0; o < 64; o++) {
      uint32 wp = s_w23p[(o + 64) * 64 + lane];
      float w2v = bf_lo(wp), w3v = bf_hi(wp);
#pragma unroll
      for (int k = 0; k < 16; k++) {
        float s = bcast(xnB[k], o);
        x2a[k] = fmaf(w2v, s, x2a[k]);
        x3a[k] = fmaf(w3v, s, x3a[k]);
      }
    }

    // ---- Phase D: x1[c] = b1[c] + sum_o w1[c,o] xn[o][0]
    float x1 = b1r;
    for (int o2 = 0; o2 < 64; o2++) {
      uint32 wp = gw1p[o2 * 64 + lane];
      x1 = fmaf(bf_lo(wp), bcast(xnA[0], o2), x1);
      x1 = fmaf(bf_hi(wp), bcast(xnB[0], o2), x1);
    }

    // ---- Phase E: xfs = x1 - x2 + ptf ; x3 += ptf
    float xfs[16];
#pragma unroll
    for (int k = 0; k < 16; k++) {
      xfs[k] = x1 - x2a[k] + ptf[k];
      x3a[k] += ptf[k];
    }

    // ---- Phase F: h[j] = relu(sum_{c,k} cw1[j, c*16+k] xfs[c][k])
    float hp[8];
#pragma unroll
    for (int j = 0; j < 8; j++) hp[j] = 0.f;
#pragma unroll
    for (int k = 0; k < 16; k++) {
#pragma unroll
      for (int j2 = 0; j2 < 4; j2++) {
        uint32 wp = gcw1p[(k * 4 + j2) * 64 + lane];
        hp[j2] = fmaf(bf_lo(wp), xfs[k], hp[j2]);
        hp[j2 + 4] = fmaf(bf_hi(wp), xfs[k], hp[j2 + 4]);
      }
    }
#pragma unroll
    for (int j = 0; j < 8; j++) {
      float v = hp[j];
#pragma unroll
      for (int s = 1; s < 64; s <<= 1) v += __shfl_xor(v, s, 64);
      hp[j] = fmaxf(v, 0.f);
    }

    // ---- Phase G: wl[l] = cb2[l] + sum_j cw2[l,j] h[j]; lane holds l=lane (A), l=lane+64 (B)
    float wlA = cb2A, wlB = cb2B;
#pragma unroll
    for (int j = 0; j < 8; j++) {
      uint32 wp = gcw2p[j * 64 + lane];
      wlA = fmaf(bf_lo(wp), hp[j], wlA);
      wlB = fmaf(bf_hi(wp), hp[j], wlB);
    }

    // ---- Phase H: softmax over k within 16-lane groups (l = g*16 + k)
    float mA = wlA, mB = wlB;
#pragma unroll
    for (int s = 1; s < 16; s <<= 1) {
      mA = fmaxf(mA, __shfl_xor(mA, s, 64));
      mB = fmaxf(mB, __shfl_xor(mB, s, 64));
    }
    float eA = __expf(wlA - mA), eB = __expf(wlB - mB);
    float sA = eA, sB = eB;
#pragma unroll
    for (int s = 1; s < 16; s <<= 1) {
      sA += __shfl_xor(sA, s, 64);
      sB += __shfl_xor(sB, s, 64);
    }
    float smA = eA / sA, smB = eB / sB;

    // ---- Phase I: om[c] = relu(sum_k w[c%8][k] x3[c][k]); w[g][k] = sm[g*16+k]
    float om = 0.f;
    const int g4 = lane & 7;
#pragma unroll
    for (int k = 0; k < 16; k++) {
      int idx = (g4 << 4) + k;
      float va = __shfl(smA, idx & 63, 64);
      float vb = __shfl(smB, idx & 63, 64);
      float wk = (g4 < 4) ? va : vb;
      om = fmaf(wk, x3a[k], om);
    }
    om = fmaxf(om, 0.f);

    // ---- Phase J: out[o] = bout[o] + identity[o] + sum_c wout[o,c] om[c]
    float outA = boutA + xnA[0];
    float outB = boutB + xnB[0];
    for (int c = 0; c < 64; c++) {
      uint32 wp = gwoutp[c * 64 + lane];
      float s = bcast(om, c);
      outA = fmaf(bf_lo(wp), s, outA);
      outB = fmaf(bf_hi(wp), s, outB);
    }

    out[((size_t)(b * 128 + lane)) * 16384 + n] = outA;
    out[((size_t)(b * 128 + lane + 64)) * 16384 + n] = outB;
  }
}

extern "C" void kernel_launch(void* const* d_in, const int* in_sizes, int n_in,
                              void* d_out, int out_size, void* d_ws, size_t ws_size,
                              hipStream_t stream) {
  const float* feats = (const float*)d_in[0];
  const float* ppfs = (const float*)d_in[1];
  const float* w0 = (const float*)d_in[2];
  const float* b0 = (const float*)d_in[3];
  const float* w1 = (const float*)d_in[4];
  const float* b1 = (const float*)d_in[5];
  const float* w2 = (const float*)d_in[6];
  const float* b2 = (const float*)d_in[7];
  const float* w3 = (const float*)d_in[8];
  const float* b3 = (const float*)d_in[9];
  const float* pw1 = (const float*)d_in[10];
  const float* pw2 = (const float*)d_in[11];
  const float* cw1 = (const float*)d_in[12];
  const float* cw2 = (const float*)d_in[13];
  const float* cb2 = (const float*)d_in[14];
  const float* wout = (const float*)d_in[15];
  const float* bout = (const float*)d_in[16];
  (void)b3; (void)in_sizes; (void)n_in; (void)out_size; (void)ws_size;

  uint32* ws = (uint32*)d_ws;

  hipLaunchKernelGGL(pack_weights_kernel, dim3(8), dim3(256), 0, stream,
                     w1, pw1, pw2, cw2, wout, cw1, ws);
  hipLaunchKernelGGL(pt_fused, dim3(NBLOCKS), dim3(256), 0, stream,
                     feats, ppfs, w0, b0, b1, w2, b2, w3, (const float*)d_in[9], cb2, bout,
                     ws, (float*)d_out);
}